// Round 3
// baseline (5930.991 us; speedup 1.0000x reference)
//
#include <hip/hip_runtime.h>
#include <hip/hip_bf16.h>

typedef __attribute__((ext_vector_type(8))) short bf16x8;
typedef __attribute__((ext_vector_type(4))) float f32x4;
typedef __attribute__((ext_vector_type(4))) short s16x4;

__device__ __forceinline__ short f2bf(float f) {
    union { float f; unsigned u; } c; c.f = f;
    unsigned u = c.u;
    u += 0x7fffu + ((u >> 16) & 1u);   // RNE
    return (short)(u >> 16);
}

// ---------------- degree / dinv ----------------
__global__ void k_deg_init(float* __restrict__ deg, int N) {
    int i = blockIdx.x * blockDim.x + threadIdx.x;
    if (i < N) deg[i] = 1.0f;   // self loop
}

__global__ void k_deg_count(const int* __restrict__ ei, float* __restrict__ deg, int E) {
    int i = blockIdx.x * blockDim.x + threadIdx.x;
    int stride = gridDim.x * blockDim.x;
    for (int e = i; e < E; e += stride) {
        atomicAdd(&deg[ei[E + e]], 1.0f);   // dst occurrences
    }
}

__global__ void k_dinv(float* __restrict__ deg, int N) {
    int i = blockIdx.x * blockDim.x + threadIdx.x;
    if (i < N) deg[i] = rsqrtf(deg[i]);
}

// ---------------- W transpose to bf16 ----------------
// W: [512][256] f32 row-major  ->  Wt: [256][512] bf16 row-major
__global__ void k_wt(const float* __restrict__ W, short* __restrict__ wt) {
    int i = blockIdx.x * blockDim.x + threadIdx.x;
    if (i < 256 * 512) {
        int col = i >> 9;        // 0..255
        int kk  = i & 511;       // 0..511
        wt[i] = f2bf(W[kk * 256 + col]);
    }
}

// ---------------- GEMM: hs = dinv[row] * (x @ W) ----------------
// 128x128 tile, 4 waves of 64x64, mfma 16x16x32 bf16, K=512.
__global__ __launch_bounds__(256) void k_gemm(const float* __restrict__ x,
                                              const short* __restrict__ wt,
                                              const float* __restrict__ dinv,
                                              float* __restrict__ hs, int M) {
    __shared__ short lsA[128 * 64];   // 16 KB, XOR-swizzled
    const int t    = threadIdx.x;
    const int lane = t & 63;
    const int w    = t >> 6;
    const int wr   = w >> 1;
    const int wc   = w & 1;
    const int r0   = blockIdx.y * 128;
    const int cb   = blockIdx.x * 128;

    f32x4 acc[4][4] = {};

    for (int k0 = 0; k0 < 512; k0 += 64) {
        __syncthreads();
        // stage A tile: 128 rows x 64 k, f32 -> bf16, swizzled LDS
        #pragma unroll
        for (int j = 0; j < 8; ++j) {
            int i   = t + 256 * j;     // float4 id within tile
            int row = i >> 4;          // 0..127
            int kq  = i & 15;          // float4 within row
            int gr  = r0 + row;
            float4 v = make_float4(0.f, 0.f, 0.f, 0.f);
            if (gr < M) v = *(const float4*)(x + (size_t)gr * 512 + (k0 + kq * 4));
            s16x4 sv;
            sv.x = f2bf(v.x); sv.y = f2bf(v.y); sv.z = f2bf(v.z); sv.w = f2bf(v.w);
            int byte = (row * 128 + kq * 8) ^ ((row & 7) << 4);
            *(s16x4*)((char*)lsA + byte) = sv;
        }
        __syncthreads();

        #pragma unroll
        for (int kk = 0; kk < 64; kk += 32) {
            bf16x8 af[4], bfr[4];
            #pragma unroll
            for (int i = 0; i < 4; ++i) {
                int lrow = wr * 64 + i * 16 + (lane & 15);
                int byte = (lrow * 128 + (kk + (lane >> 4) * 8) * 2) ^ ((lrow & 7) << 4);
                af[i] = *(const bf16x8*)((const char*)lsA + byte);
            }
            #pragma unroll
            for (int j2 = 0; j2 < 4; ++j2) {
                int col = cb + wc * 64 + j2 * 16 + (lane & 15);
                bfr[j2] = *(const bf16x8*)(wt + (size_t)col * 512 + (k0 + kk + ((lane >> 4) * 8)));
            }
            #pragma unroll
            for (int i = 0; i < 4; ++i)
                #pragma unroll
                for (int j2 = 0; j2 < 4; ++j2)
                    acc[i][j2] = __builtin_amdgcn_mfma_f32_16x16x32_bf16(af[i], bfr[j2], acc[i][j2], 0, 0, 0);
        }
    }

    // epilogue: hs = acc * dinv[row]   (C/D: col=lane&15, row=(lane>>4)*4+reg)
    #pragma unroll
    for (int i = 0; i < 4; ++i) {
        int rbase = r0 + wr * 64 + i * 16 + ((lane >> 4) * 4);
        #pragma unroll
        for (int j2 = 0; j2 < 4; ++j2) {
            int c = cb + wc * 64 + j2 * 16 + (lane & 15);
            #pragma unroll
            for (int r = 0; r < 4; ++r) {
                int rr = rbase + r;
                if (rr < M) hs[(size_t)rr * 256 + c] = acc[i][j2][r] * dinv[rr];
            }
        }
    }
}

// ---------------- edge scatter: out[dst] += hs[src] ----------------
__global__ __launch_bounds__(256) void k_scatter(const int* __restrict__ ei,
                                                 const float* __restrict__ hs,
                                                 float* __restrict__ out, int E) {
    int wave   = (blockIdx.x * blockDim.x + threadIdx.x) >> 6;
    int lane   = threadIdx.x & 63;
    int nwaves = (gridDim.x * blockDim.x) >> 6;
    for (int e = wave; e < E; e += nwaves) {
        int s = ei[e];
        int d = ei[E + e];
        float4 v = *(const float4*)(hs + (size_t)s * 256 + lane * 4);
        float* o = out + (size_t)d * 256 + lane * 4;
        atomicAdd(o + 0, v.x);
        atomicAdd(o + 1, v.y);
        atomicAdd(o + 2, v.z);
        atomicAdd(o + 3, v.w);
    }
}

// ---------------- final: out = PReLU(dinv[v]*(out + hs) + b) ----------------
__global__ void k_final(float* __restrict__ out, const float* __restrict__ hs,
                        const float* __restrict__ dinv, const float* __restrict__ b,
                        const float* __restrict__ pa, int total4) {
    int i = blockIdx.x * blockDim.x + threadIdx.x;
    int stride = gridDim.x * blockDim.x;
    float a = pa[0];
    for (; i < total4; i += stride) {
        float4 o = ((const float4*)out)[i];
        float4 h = ((const float4*)hs)[i];
        int base = i * 4;
        int v = base >> 8;
        int d = base & 255;
        float dv = dinv[v];
        float4 bb = *(const float4*)(b + d);
        float r0 = dv * (o.x + h.x) + bb.x;
        float r1 = dv * (o.y + h.y) + bb.y;
        float r2 = dv * (o.z + h.z) + bb.z;
        float r3 = dv * (o.w + h.w) + bb.w;
        float4 res;
        res.x = r0 > 0.f ? r0 : a * r0;
        res.y = r1 > 0.f ? r1 : a * r1;
        res.z = r2 > 0.f ? r2 : a * r2;
        res.w = r3 > 0.f ? r3 : a * r3;
        ((float4*)out)[i] = res;
    }
}

extern "C" void kernel_launch(void* const* d_in, const int* in_sizes, int n_in,
                              void* d_out, int out_size, void* d_ws, size_t ws_size,
                              hipStream_t stream) {
    const float* x  = (const float*)d_in[0];
    const int*   ei = (const int*)d_in[1];
    const float* W  = (const float*)d_in[2];
    const float* b  = (const float*)d_in[3];
    const float* pa = (const float*)d_in[4];

    const int N = in_sizes[0] / 512;     // 100000
    const int E = in_sizes[1] / 2;       // 1600000

    // workspace layout
    char* ws = (char*)d_ws;
    size_t offDeg = 0;
    size_t offWt  = ((size_t)N * 4 + 255) & ~(size_t)255;           // after deg
    size_t offHs  = (offWt + 256 * 512 * 2 + 255) & ~(size_t)255;   // after Wt
    float* deg = (float*)(ws + offDeg);      // becomes dinv in place
    short* wt  = (short*)(ws + offWt);
    float* hs  = (float*)(ws + offHs);

    float* out = (float*)d_out;

    // 1) degree (incl. self loop)
    k_deg_init<<<(N + 255) / 256, 256, 0, stream>>>(deg, N);
    k_deg_count<<<2048, 256, 0, stream>>>(ei, deg, E);
    k_dinv<<<(N + 255) / 256, 256, 0, stream>>>(deg, N);

    // 2) W^T -> bf16
    k_wt<<<(256 * 512 + 255) / 256, 256, 0, stream>>>(W, wt);

    // 3) hs = dinv * (x @ W)
    dim3 ggrid(2, (N + 127) / 128);
    k_gemm<<<ggrid, 256, 0, stream>>>(x, wt, deg, hs, N);

    // 4) out = sum_{edges} hs[src]
    hipMemsetAsync(d_out, 0, (size_t)out_size * sizeof(float), stream);
    k_scatter<<<16384, 256, 0, stream>>>(ei, hs, out, E);

    // 5) out = PReLU(dinv*(out + hs) + b)
    k_final<<<2048, 256, 0, stream>>>(out, hs, deg, b, pa, (N * 256) / 4);
}

// Round 5
// 861.381 us; speedup vs baseline: 6.8854x; 6.8854x over previous
//
#include <hip/hip_runtime.h>
#include <hip/hip_bf16.h>

typedef __attribute__((ext_vector_type(8))) short bf16x8;
typedef __attribute__((ext_vector_type(4))) float f32x4;
typedef __attribute__((ext_vector_type(4))) short s16x4;

__device__ __forceinline__ short f2bf(float f) {
    union { float f; unsigned u; } c; c.f = f;
    unsigned u = c.u;
    u += 0x7fffu + ((u >> 16) & 1u);   // RNE
    return (short)(u >> 16);
}
__device__ __forceinline__ float bf2f(short s) {
    union { unsigned u; float f; } c; c.u = ((unsigned)(unsigned short)s) << 16;
    return c.f;
}

// ---------------- count in-degree (real edges only) ----------------
__global__ void k_count(const int* __restrict__ ei, int* __restrict__ cnt, int E) {
    int i = blockIdx.x * blockDim.x + threadIdx.x;
    int stride = gridDim.x * blockDim.x;
    for (int e = i; e < E; e += stride) atomicAdd(&cnt[ei[E + e]], 1);
}

// ---------------- allocate buckets + dinv ----------------
__global__ void k_alloc(const int* __restrict__ cnt, int* __restrict__ start,
                        float* __restrict__ dinv, int* __restrict__ cursor, int N) {
    int i = blockIdx.x * blockDim.x + threadIdx.x;
    if (i < N) {
        int c = cnt[i];
        start[i] = atomicAdd(cursor, c);
        dinv[i] = rsqrtf((float)(c + 1));   // +1 self loop
    }
}

// ---------------- fill buckets: elist[start[d] + cur[d]++] = s ----------------
__global__ void k_fill(const int* __restrict__ ei, const int* __restrict__ start,
                       int* __restrict__ cur, int* __restrict__ elist, int E) {
    int i = blockIdx.x * blockDim.x + threadIdx.x;
    int stride = gridDim.x * blockDim.x;
    for (int e = i; e < E; e += stride) {
        int s = ei[e];
        int d = ei[E + e];
        int pos = start[d] + atomicAdd(&cur[d], 1);
        elist[pos] = s;
    }
}

// ---------------- W transpose to bf16 ----------------
__global__ void k_wt(const float* __restrict__ W, short* __restrict__ wt) {
    int i = blockIdx.x * blockDim.x + threadIdx.x;
    if (i < 256 * 512) {
        int col = i >> 9;
        int kk  = i & 511;
        wt[i] = f2bf(W[kk * 256 + col]);
    }
}

// ---------------- GEMM: hs(bf16) = dinv[row] * (x @ W) ----------------
__global__ __launch_bounds__(256) void k_gemm(const float* __restrict__ x,
                                              const short* __restrict__ wt,
                                              const float* __restrict__ dinv,
                                              short* __restrict__ hs, int M) {
    __shared__ short lsA[128 * 64];   // 16 KB, XOR-swizzled
    const int t    = threadIdx.x;
    const int lane = t & 63;
    const int w    = t >> 6;
    const int wr   = w >> 1;
    const int wc   = w & 1;
    const int r0   = blockIdx.y * 128;
    const int cb   = blockIdx.x * 128;

    f32x4 acc[4][4] = {};

    for (int k0 = 0; k0 < 512; k0 += 64) {
        __syncthreads();
        #pragma unroll
        for (int j = 0; j < 8; ++j) {
            int i   = t + 256 * j;
            int row = i >> 4;
            int kq  = i & 15;
            int gr  = r0 + row;
            float4 v = make_float4(0.f, 0.f, 0.f, 0.f);
            if (gr < M) v = *(const float4*)(x + (size_t)gr * 512 + (k0 + kq * 4));
            s16x4 sv;
            sv.x = f2bf(v.x); sv.y = f2bf(v.y); sv.z = f2bf(v.z); sv.w = f2bf(v.w);
            int byte = (row * 128 + kq * 8) ^ ((row & 7) << 4);
            *(s16x4*)((char*)lsA + byte) = sv;
        }
        __syncthreads();

        #pragma unroll
        for (int kk = 0; kk < 64; kk += 32) {
            bf16x8 af[4], bfr[4];
            #pragma unroll
            for (int i = 0; i < 4; ++i) {
                int lrow = wr * 64 + i * 16 + (lane & 15);
                int byte = (lrow * 128 + (kk + (lane >> 4) * 8) * 2) ^ ((lrow & 7) << 4);
                af[i] = *(const bf16x8*)((const char*)lsA + byte);
            }
            #pragma unroll
            for (int j2 = 0; j2 < 4; ++j2) {
                int col = cb + wc * 64 + j2 * 16 + (lane & 15);
                bfr[j2] = *(const bf16x8*)(wt + (size_t)col * 512 + (k0 + kk + ((lane >> 4) * 8)));
            }
            #pragma unroll
            for (int i = 0; i < 4; ++i)
                #pragma unroll
                for (int j2 = 0; j2 < 4; ++j2)
                    acc[i][j2] = __builtin_amdgcn_mfma_f32_16x16x32_bf16(af[i], bfr[j2], acc[i][j2], 0, 0, 0);
        }
    }

    // epilogue: hs = bf16(acc * dinv[row])   (C/D: col=lane&15, row=(lane>>4)*4+reg)
    #pragma unroll
    for (int i = 0; i < 4; ++i) {
        int rbase = r0 + wr * 64 + i * 16 + ((lane >> 4) * 4);
        #pragma unroll
        for (int j2 = 0; j2 < 4; ++j2) {
            int c = cb + wc * 64 + j2 * 16 + (lane & 15);
            #pragma unroll
            for (int r = 0; r < 4; ++r) {
                int rr = rbase + r;
                if (rr < M) hs[(size_t)rr * 256 + c] = f2bf(acc[i][j2][r] * dinv[rr]);
            }
        }
    }
}

// ---------------- gather + finalize: one wave per node ----------------
// out[v] = PReLU(dinv[v] * (hs[v] + sum_{s in in(v)} hs[s]) + b)
__global__ __launch_bounds__(256) void k_gather(const int* __restrict__ start,
                                                const int* __restrict__ cnt,
                                                const int* __restrict__ elist,
                                                const short* __restrict__ hs,
                                                const float* __restrict__ dinv,
                                                const float* __restrict__ b,
                                                const float* __restrict__ pa,
                                                float* __restrict__ out, int N) {
    int wave = (blockIdx.x * blockDim.x + threadIdx.x) >> 6;
    int lane = threadIdx.x & 63;
    if (wave >= N) return;
    int v = wave;

    float a = pa[0];
    int n0 = start[v];
    int c  = cnt[v];

    // self contribution
    s16x4 sv = *(const s16x4*)(hs + (size_t)v * 256 + lane * 4);
    float a0 = bf2f(sv.x), a1 = bf2f(sv.y), a2 = bf2f(sv.z), a3 = bf2f(sv.w);

    for (int e = 0; e < c; ++e) {
        int s = elist[n0 + e];
        s16x4 r = *(const s16x4*)(hs + (size_t)s * 256 + lane * 4);
        a0 += bf2f(r.x); a1 += bf2f(r.y); a2 += bf2f(r.z); a3 += bf2f(r.w);
    }

    float dv = dinv[v];
    float4 bb = *(const float4*)(b + lane * 4);
    float r0 = dv * a0 + bb.x;
    float r1 = dv * a1 + bb.y;
    float r2 = dv * a2 + bb.z;
    float r3 = dv * a3 + bb.w;
    float4 res;
    res.x = r0 > 0.f ? r0 : a * r0;
    res.y = r1 > 0.f ? r1 : a * r1;
    res.z = r2 > 0.f ? r2 : a * r2;
    res.w = r3 > 0.f ? r3 : a * r3;
    *(float4*)(out + (size_t)v * 256 + lane * 4) = res;
}

extern "C" void kernel_launch(void* const* d_in, const int* in_sizes, int n_in,
                              void* d_out, int out_size, void* d_ws, size_t ws_size,
                              hipStream_t stream) {
    const float* x  = (const float*)d_in[0];
    const int*   ei = (const int*)d_in[1];
    const float* W  = (const float*)d_in[2];
    const float* b  = (const float*)d_in[3];
    const float* pa = (const float*)d_in[4];

    const int N = in_sizes[0] / 512;     // 100000
    const int E = in_sizes[1] / 2;       // 1600000

    // workspace layout (all 256B aligned)
    char* ws = (char*)d_ws;
    size_t off = 0;
    auto alloc = [&](size_t bytes) { size_t o = off; off = (off + bytes + 255) & ~(size_t)255; return o; };
    // [cnt N][cur N][cursor 1] contiguous -> single memset
    size_t offMeta  = alloc((size_t)(2 * N + 1) * 4);
    size_t offStart = alloc((size_t)N * 4);
    size_t offDinv  = alloc((size_t)N * 4);
    size_t offElist = alloc((size_t)E * 4);
    size_t offWt    = alloc((size_t)256 * 512 * 2);
    size_t offHs    = alloc((size_t)N * 256 * 2);

    int*   cnt    = (int*)(ws + offMeta);
    int*   cur    = cnt + N;
    int*   cursor = cnt + 2 * N;
    int*   start  = (int*)(ws + offStart);
    float* dinv   = (float*)(ws + offDinv);
    int*   elist  = (int*)(ws + offElist);
    short* wt     = (short*)(ws + offWt);
    short* hs     = (short*)(ws + offHs);
    float* out    = (float*)d_out;

    // 0) zero counters
    hipMemsetAsync(cnt, 0, (size_t)(2 * N + 1) * 4, stream);

    // 1) in-degree counts (dst of real edges)
    k_count<<<2048, 256, 0, stream>>>(ei, cnt, E);

    // 2) bucket allocation + dinv
    k_alloc<<<(N + 255) / 256, 256, 0, stream>>>(cnt, start, dinv, cursor, N);

    // 3) fill CSR buckets
    k_fill<<<2048, 256, 0, stream>>>(ei, start, cur, elist, E);

    // 4) W^T -> bf16 (independent; can overlap in graph)
    k_wt<<<(256 * 512 + 255) / 256, 256, 0, stream>>>(W, wt);

    // 5) hs = bf16(dinv * (x @ W))
    dim3 ggrid(2, (N + 127) / 128);
    k_gemm<<<ggrid, 256, 0, stream>>>(x, wt, dinv, hs, N);

    // 6) gather + dinv + bias + PReLU, one write per output row
    k_gather<<<(N + 3) / 4, 256, 0, stream>>>(start, cnt, elist, hs, dinv, b, pa, out, N);
}